// Round 4
// baseline (179.667 us; speedup 1.0000x reference)
//
#include <hip/hip_runtime.h>
#include <math.h>

#define DD   128
#define DI   170
#define BB   4096
#define NNEG 5
#define ROWS 8
#define NBLK (BB / ROWS)            // 512 blocks -> 2 blocks/CU
#define TASKS (ROWS * (1 + NNEG))   // 48 logit tasks per block
#define TPW  (TASKS / 4)            // 12 per wave
#define SQRT_D 11.3137084989847603904f   // sqrt(128)
#define EMB_PITCH 132               // padded LDS row (conflict-free e4 reads)
#define X_PITCH   172               // padded s_x row

__device__ __forceinline__ float wave_bcast_sum(float v) {
#pragma unroll
    for (int m = 1; m < 64; m <<= 1) v += __shfl_xor(v, m, 64);
    return v;
}

// Prep: inverse L2 norms only (no transposes -- R3 showed ws round-trips hurt).
// Blocks 0..84: 4 row-norms each (W_hidden/W_gate). Block 85: W_ff_out column
// norms (coalesced row-walk) + zero the output accumulator.
__global__ __launch_bounds__(256) void norms_kernel(
    const float* __restrict__ W_hidden,
    const float* __restrict__ W_gate,
    const float* __restrict__ W_ff_out,
    float* __restrict__ inv_h,
    float* __restrict__ inv_g,
    float* __restrict__ inv_f,
    float* __restrict__ out)
{
    if (blockIdx.x < 85) {
        const int wave = threadIdx.x >> 6;
        const int lane = threadIdx.x & 63;
        const int v = blockIdx.x * 4 + wave;          // 0 .. 339
        const float* W = (v < DI) ? W_hidden : W_gate;
        const int row = (v < DI) ? v : v - DI;
        float2 p = ((const float2*)(W + (long)row * DD))[lane];
        float s = wave_bcast_sum(p.x * p.x + p.y * p.y);
        if (lane == 0) {
            float inv = rsqrtf(s);
            if (v < DI) inv_h[row] = inv; else inv_g[row] = inv;
        }
    } else {
        if (threadIdx.x == 0) out[0] = 0.0f;
        const int c = threadIdx.x;                    // column of W_ff_out (D x DI)
        if (c < DI) {
            float s = 0.0f;
#pragma unroll 4
            for (int d = 0; d < DD; ++d) {
                float a = W_ff_out[(long)d * DI + c]; // coalesced across threads
                s += a * a;
            }
            inv_f[c] = rsqrtf(s);
        }
    }
}

__global__ __launch_bounds__(256) void main_kernel(
    const int*   __restrict__ input_ids,
    const int*   __restrict__ target_ids,
    const int*   __restrict__ neg_ids,
    const float* __restrict__ W_in,
    const float* __restrict__ W_out,
    const float* __restrict__ W_hidden,
    const float* __restrict__ W_gate,
    const float* __restrict__ W_ff_out,
    const float* __restrict__ hidden_scale,
    const float* __restrict__ gate_scale,
    const float* __restrict__ logit_scale,
    const float* __restrict__ inv_h,
    const float* __restrict__ inv_g,
    const float* __restrict__ inv_f,
    float* __restrict__ out)
{
    __shared__ __align__(16) float s_emb[ROWS][EMB_PITCH];  // padded: e4 reads conflict-free
    __shared__ __align__(16) float s_x[ROWS][X_PITCH];      // padded: <=2-way on writes
    __shared__ __align__(16) float s_xout[ROWS][DD];
    __shared__ float s_red[4];

    const int tid  = threadIdx.x;
    const int wave = tid >> 6;
    const int lane = tid & 63;
    const int b0   = blockIdx.x * ROWS;

    // ---- Phase 1: gather + l2-normalize input embeddings into LDS ----
#pragma unroll
    for (int k = 0; k < ROWS / 4; ++k) {
        const int r  = wave + 4 * k;
        const int id = input_ids[b0 + r];
        float2 p = ((const float2*)(W_in + (long)id * DD))[lane];
        float s  = wave_bcast_sum(p.x * p.x + p.y * p.y);
        float inv = rsqrtf(s);
        s_emb[r][2 * lane]     = p.x * inv;
        s_emb[r][2 * lane + 1] = p.y * inv;
    }
    __syncthreads();

    // ---- Phase 2: all 256 threads active. thread = (r = tid&7, ig = tid>>3).
    //      Each thread computes x[r][i] for i = ig + 32k, k = 0..5.
    //      Weight loads are 8-lane broadcast (8 unique lines/instr vs 64 in R2);
    //      one e4 LDS read per d4 serves all 6 i's; 12 independent FMA chains. ----
    {
        const int r  = tid & 7;
        const int ig = tid >> 3;                 // 0..31
        int idx[6];
#pragma unroll
        for (int k = 0; k < 6; ++k) idx[k] = ig + 32 * k;
        if (idx[5] > DI - 1) idx[5] = DI - 1;    // clamp (write guarded below)

        float ah[6], ag[6];
#pragma unroll
        for (int k = 0; k < 6; ++k) { ah[k] = 0.0f; ag[k] = 0.0f; }

        for (int d4 = 0; d4 < DD / 4; ++d4) {
            float4 e4 = *(const float4*)&s_emb[r][4 * d4];
#pragma unroll
            for (int k = 0; k < 6; ++k) {
                float4 h4 = *(const float4*)(W_hidden + (long)idx[k] * DD + 4 * d4);
                float4 g4 = *(const float4*)(W_gate   + (long)idx[k] * DD + 4 * d4);
                ah[k] += e4.x * h4.x + e4.y * h4.y + e4.z * h4.z + e4.w * h4.w;
                ag[k] += e4.x * g4.x + e4.y * g4.y + e4.z * g4.z + e4.w * g4.w;
            }
        }
#pragma unroll
        for (int k = 0; k < 6; ++k) {
            const int i = idx[k];
            const float hs = hidden_scale[i] * inv_h[i];
            const float gs = gate_scale[i]   * inv_g[i] * SQRT_D;
            const float h = ah[k] * hs;
            const float g = ag[k] * gs;
            const float x = (g / (1.0f + __expf(-g))) * h;   // silu(g) * h
            if (k < 5 || ig < DI - 160)                      // guard clamped tail
                s_x[r][i] = x * inv_f[i];
        }
    }
    __syncthreads();

    // ---- Phase 2b: xout[r][dd] = sum_i x[r][i] * W_ff_out[dd][i].
    //      thread = (dd = tid>>1, rq = tid&1; 4 rows each):
    //      Wf loads are 32 unique rows/instr (vs 64 in R2), reused over 4 rows. ----
    {
        const int dd = tid >> 1;     // 0..127
        const int rq = tid & 1;      // rows rq*4 .. rq*4+3
        float acc[4];
#pragma unroll
        for (int j = 0; j < 4; ++j) acc[j] = 0.0f;
        const float2* wrow = (const float2*)(W_ff_out + (long)dd * DI);  // 680B rows: 8B aligned
#pragma unroll 5
        for (int i2 = 0; i2 < DI / 2; ++i2) {
            float2 wf = wrow[i2];
#pragma unroll
            for (int j = 0; j < 4; ++j) {
                float2 xv = *(const float2*)&s_x[rq * 4 + j][2 * i2];  // 8-addr broadcast
                acc[j] += xv.x * wf.x + xv.y * wf.y;
            }
        }
#pragma unroll
        for (int j = 0; j < 4; ++j) s_xout[rq * 4 + j][dd] = acc[j];
    }
    __syncthreads();

    // ---- Phase 3: gathered logits + negative-sampling loss.
    //      Load phase first (all 12 W_out row-halves in flight), then reduce. ----
    float dotp[TPW], ssp[TPW], lsc[TPW];
    const int tbase = wave * TPW;
#pragma unroll
    for (int k = 0; k < TPW; ++k) {
        const int t  = tbase + k;
        const int r  = t / (1 + NNEG);
        const int jj = t % (1 + NNEG);
        const int bidx = b0 + r;
        const int id = (jj == 0) ? target_ids[bidx] : neg_ids[bidx * NNEG + jj - 1];
        const float* wrow = W_out + (long)id * DD;
        float w0 = wrow[lane], w1 = wrow[64 + lane];
        float x0 = s_xout[r][lane], x1 = s_xout[r][64 + lane];
        dotp[k] = w0 * x0 + w1 * x1;
        ssp[k]  = w0 * w0 + w1 * w1;
        lsc[k]  = logit_scale[id];
    }
    float wacc = 0.0f;
#pragma unroll
    for (int k = 0; k < TPW; ++k) {
        float dot = dotp[k], ss = ssp[k];
#pragma unroll
        for (int m = 1; m < 64; m <<= 1) {
            dot += __shfl_xor(dot, m, 64);
            ss  += __shfl_xor(ss,  m, 64);
        }
        const int jj = (tbase + k) % (1 + NNEG);
        const float logit = dot * rsqrtf(ss) * lsc[k] * SQRT_D;
        const float z  = (jj == 0) ? logit : -logit;
        const float ls = fminf(z, 0.0f) - log1pf(__expf(-fabsf(z)));   // stable log_sigmoid
        wacc += (jj == 0) ? ls * (1.0f / BB) : ls * (1.0f / (BB * NNEG));
    }
    if (lane == 0) s_red[wave] = wacc;
    __syncthreads();
    if (tid == 0) {
        float tot = s_red[0] + s_red[1] + s_red[2] + s_red[3];
        atomicAdd(out, -tot);
    }
}

extern "C" void kernel_launch(void* const* d_in, const int* in_sizes, int n_in,
                              void* d_out, int out_size, void* d_ws, size_t ws_size,
                              hipStream_t stream) {
    (void)in_sizes; (void)n_in; (void)out_size; (void)ws_size;
    const int*   input_ids    = (const int*)  d_in[0];
    const int*   target_ids   = (const int*)  d_in[1];
    const int*   neg_ids      = (const int*)  d_in[2];
    const float* W_in         = (const float*)d_in[3];
    const float* W_out        = (const float*)d_in[4];
    const float* W_hidden     = (const float*)d_in[5];
    const float* W_gate       = (const float*)d_in[6];
    const float* W_ff_out     = (const float*)d_in[7];
    const float* hidden_scale = (const float*)d_in[8];
    const float* gate_scale   = (const float*)d_in[9];
    const float* logit_scale  = (const float*)d_in[10];
    float* out   = (float*)d_out;
    float* inv_h = (float*)d_ws;
    float* inv_g = inv_h + DI;
    float* inv_f = inv_g + DI;

    norms_kernel<<<86, 256, 0, stream>>>(W_hidden, W_gate, W_ff_out,
                                         inv_h, inv_g, inv_f, out);
    main_kernel<<<NBLK, 256, 0, stream>>>(input_ids, target_ids, neg_ids,
                                          W_in, W_out, W_hidden, W_gate, W_ff_out,
                                          hidden_scale, gate_scale, logit_scale,
                                          inv_h, inv_g, inv_f, out);
}